// Round 12
// baseline (362.381 us; speedup 1.0000x reference)
//
#include <hip/hip_runtime.h>
#include <stdint.h>

// Fused single-head attention + LN + mean-pool, MI355X (gfx950).
// Precision: 1-pass bf16 MFMA everywhere (QKV, QK^T, P@V); absmax floor
// ~6.7e-4 (P/V bf16 quant), validated r2-r11. Opart bf16 x2 split-K slabs.
// Softmax shift c_i = 5|q_i|+10 (cancels exactly; tail-safe).
// Schedule: fat 1-phase, 128^2 tiles (256-wide tiles thrash L2: r6/r10;
// XCD swizzle breaks B-panel L2 slicing: r7; shallow 2-phase loses: r3).
// Round 12: P is near-one-hot (unscaled softmax) -> k_pv skips dead
// (16-row-group x 64-col-chunk) work via mass bitmasks derived from the
// per-chunk partial sums k_scores already produces. Skipped relative mass
// per row <= 128 * 1e-7 -> output error ~6e-5.

#define NR 8192
#define DI 512
#define ACT_THR 1e-7f

typedef float f32x4 __attribute__((ext_vector_type(4)));
typedef short short8 __attribute__((ext_vector_type(8)));
typedef unsigned short u16;
typedef unsigned long long u64;

__device__ __forceinline__ u16 f2bf(float f) {
  union { float f; unsigned u; } v; v.f = f;
  unsigned u = v.u;
  return (u16)((u + 0x7FFFu + ((u >> 16) & 1u)) >> 16);  // RNE
}
__device__ __forceinline__ float bf2f(u16 b) {
  union { unsigned u; float f; } v; v.u = ((unsigned)b) << 16;
  return v.f;
}

__device__ __forceinline__ void load_lds16(const void* g, void* l) {
  __builtin_amdgcn_global_load_lds(
      (const __attribute__((address_space(1))) unsigned int*)g,
      (__attribute__((address_space(3))) unsigned int*)l, 16, 0, 0);
}

// ---------------- K0: convert inputs to bf16 ----------------
__global__ void k_prep(const float* __restrict__ x,
                       const float* __restrict__ wq,
                       const float* __restrict__ wk,
                       const float* __restrict__ wv,
                       u16* __restrict__ xhi, u16* __restrict__ whi) {
  int tid = blockIdx.x * 256 + threadIdx.x;
  int nth = gridDim.x * 256;
  const float4* x4 = (const float4*)x;
  ushort4* xh4 = (ushort4*)xhi;
  for (int i = tid; i < NR * DI / 4; i += nth) {
    float4 v = x4[i];
    ushort4 h;
    h.x = f2bf(v.x); h.y = f2bf(v.y); h.z = f2bf(v.z); h.w = f2bf(v.w);
    xh4[i] = h;
  }
  ushort4* wh4 = (ushort4*)whi;
  const int wq4 = DI * DI / 4;
  for (int i = tid; i < 3 * wq4; i += nth) {
    int z = i / wq4, j = i - z * wq4;
    const float4* src = (const float4*)(z == 0 ? wq : z == 1 ? wk : wv);
    float4 v = src[j];
    ushort4 h;
    h.x = f2bf(v.x); h.y = f2bf(v.y); h.z = f2bf(v.z); h.w = f2bf(v.w);
    wh4[i] = h;
  }
}

// ---------------- K1: q/k/v = xhi @ Whi^T + b (z = 0/1/2) -----------------
__global__ __launch_bounds__(256, 4) void k_qkv(
    const u16* __restrict__ xhi, const u16* __restrict__ whi,
    const float* __restrict__ bq, const float* __restrict__ bk,
    const float* __restrict__ bv,
    u16* __restrict__ qhi, u16* __restrict__ khi,
    u16* __restrict__ vt, float* __restrict__ qnp) {
  __shared__ __align__(16) u16 sA[128 * 64], sB[128 * 64];
  const int z = blockIdx.z;
  const int m0 = blockIdx.y * 128, n0 = blockIdx.x * 128;
  const int lane = threadIdx.x & 63, wid = threadIdx.x >> 6;
  const int wr = wid >> 1, wc = wid & 1;
  const u16* Wh = whi + (size_t)z * DI * DI;
  f32x4 acc[4][4] = {};
  const bool isA = wid < 2;
  const u16* gS = isA ? xhi : Wh;
  u16* Dst = isA ? sA : sB;
  const int gb = isA ? m0 : n0;
  const int rbase = (wid & 1) * 64;

  for (int kt = 0; kt < 8; ++kt) {
#pragma unroll
    for (int c = 0; c < 8; ++c) {
      int row = rbase + c * 8 + (lane >> 3);
      int srck = kt * 64 + (((lane & 7) ^ (row & 7)) << 3);
      load_lds16(gS + (size_t)(gb + row) * DI + srck,
                 (char*)Dst + (size_t)(rbase + c * 8) * 128);
    }
    __syncthreads();
#pragma unroll
    for (int dt = 0; dt < 2; ++dt) {
      short8 a[4], b[4];
      int kb = dt * 64 + ((lane >> 4) << 4);
#pragma unroll
      for (int t = 0; t < 4; ++t) {
        int ra = wr * 64 + t * 16 + (lane & 15);
        a[t] = *(const short8*)((const char*)sA + ra * 128 + (kb ^ ((ra & 7) << 4)));
        int rb = wc * 64 + t * 16 + (lane & 15);
        b[t] = *(const short8*)((const char*)sB + rb * 128 + (kb ^ ((rb & 7) << 4)));
      }
#pragma unroll
      for (int mi = 0; mi < 4; ++mi)
#pragma unroll
        for (int ni = 0; ni < 4; ++ni)
          acc[mi][ni] = __builtin_amdgcn_mfma_f32_16x16x32_bf16(a[mi], b[ni], acc[mi][ni], 0, 0, 0);
    }
    __syncthreads();
  }

  const float* bias = (z == 0) ? bq : (z == 1) ? bk : bv;
  if (z < 2) {
    u16* oh = (z == 0) ? qhi : khi;
    float rowsq[4][4] = {};
#pragma unroll
    for (int ni = 0; ni < 4; ++ni) {
      int col = n0 + wc * 64 + ni * 16 + (lane & 15);
      float b = bias[col];
#pragma unroll
      for (int mi = 0; mi < 4; ++mi)
#pragma unroll
        for (int r = 0; r < 4; ++r) {
          int row = m0 + wr * 64 + mi * 16 + (lane >> 4) * 4 + r;
          float v = acc[mi][ni][r] + b;
          oh[(size_t)row * DI + col] = f2bf(v);
          if (z == 0) rowsq[mi][r] += v * v;
        }
    }
    if (z == 0) {
#pragma unroll
      for (int mi = 0; mi < 4; ++mi)
#pragma unroll
        for (int r = 0; r < 4; ++r) {
          float s = rowsq[mi][r];
          s += __shfl_xor(s, 1); s += __shfl_xor(s, 2);
          s += __shfl_xor(s, 4); s += __shfl_xor(s, 8);
          if ((lane & 15) == 0) {
            int row = m0 + wr * 64 + mi * 16 + (lane >> 4) * 4 + r;
            qnp[(size_t)(blockIdx.x * 2 + wc) * NR + row] = s;
          }
        }
    }
  } else {
#pragma unroll
    for (int ni = 0; ni < 4; ++ni) {
      int col = n0 + wc * 64 + ni * 16 + (lane & 15);
      float b = bias[col];
#pragma unroll
      for (int mi = 0; mi < 4; ++mi) {
        int rowb = m0 + wr * 64 + mi * 16 + (lane >> 4) * 4;
        ushort4 pk;
        pk.x = f2bf(acc[mi][ni][0] + b);
        pk.y = f2bf(acc[mi][ni][1] + b);
        pk.z = f2bf(acc[mi][ni][2] + b);
        pk.w = f2bf(acc[mi][ni][3] + b);
        *(ushort4*)(vt + (size_t)col * NR + rowb) = pk;
      }
    }
  }
}

// ---------------- K1b: c_i = 5*|q_i| + 10 ----------------
__global__ void k_cvec(const float* __restrict__ qnp, float* __restrict__ cvec) {
  int i = blockIdx.x * 256 + threadIdx.x;  // grid 32 x 256 = 8192
  float s = 0.f;
#pragma unroll
  for (int t = 0; t < 8; ++t) s += qnp[(size_t)t * NR + i];
  cvec[i] = 5.0f * sqrtf(s) + 10.f;
}

// ---------------- K2: P = exp(qhi·khi - c_row), partial row sums ----------
// psum[t][row], t = bx*2+wc: mass of 64-col chunk t = cols [t*64, t*64+64).
__global__ __launch_bounds__(256, 4) void k_scores(
    const u16* __restrict__ qhi, const u16* __restrict__ khi,
    const float* __restrict__ cvec,
    u16* __restrict__ P, float* __restrict__ psum) {
  __shared__ __align__(16) u16 sA[128 * 64], sB[128 * 64];
  const int m0 = blockIdx.y * 128, n0 = blockIdx.x * 128;
  const int lane = threadIdx.x & 63, wid = threadIdx.x >> 6;
  const int wr = wid >> 1, wc = wid & 1;
  f32x4 acc[4][4] = {};
  const bool isA = wid < 2;
  const u16* gS = isA ? qhi : khi;
  u16* Dst = isA ? sA : sB;
  const int gb = isA ? m0 : n0;
  const int rbase = (wid & 1) * 64;

  for (int kt = 0; kt < 8; ++kt) {
#pragma unroll
    for (int c = 0; c < 8; ++c) {
      int row = rbase + c * 8 + (lane >> 3);
      int srck = kt * 64 + (((lane & 7) ^ (row & 7)) << 3);
      load_lds16(gS + (size_t)(gb + row) * DI + srck,
                 (char*)Dst + (size_t)(rbase + c * 8) * 128);
    }
    __syncthreads();
#pragma unroll
    for (int dt = 0; dt < 2; ++dt) {
      short8 a[4], b[4];
      int kb = dt * 64 + ((lane >> 4) << 4);
#pragma unroll
      for (int t = 0; t < 4; ++t) {
        int ra = wr * 64 + t * 16 + (lane & 15);
        a[t] = *(const short8*)((const char*)sA + ra * 128 + (kb ^ ((ra & 7) << 4)));
        int rb = wc * 64 + t * 16 + (lane & 15);
        b[t] = *(const short8*)((const char*)sB + rb * 128 + (kb ^ ((rb & 7) << 4)));
      }
#pragma unroll
      for (int mi = 0; mi < 4; ++mi)
#pragma unroll
        for (int ni = 0; ni < 4; ++ni)
          acc[mi][ni] = __builtin_amdgcn_mfma_f32_16x16x32_bf16(a[mi], b[ni], acc[mi][ni], 0, 0, 0);
    }
    __syncthreads();
  }

  float cr[4][4];
#pragma unroll
  for (int mi = 0; mi < 4; ++mi)
#pragma unroll
    for (int r = 0; r < 4; ++r)
      cr[mi][r] = cvec[m0 + wr * 64 + mi * 16 + (lane >> 4) * 4 + r];

  float ps[4][4] = {};
#pragma unroll
  for (int ni = 0; ni < 4; ++ni) {
    int col = n0 + wc * 64 + ni * 16 + (lane & 15);
#pragma unroll
    for (int mi = 0; mi < 4; ++mi)
#pragma unroll
      for (int r = 0; r < 4; ++r) {
        int row = m0 + wr * 64 + mi * 16 + (lane >> 4) * 4 + r;
        float a = fminf(acc[mi][ni][r] - cr[mi][r], 60.f);  // overflow guard
        float p = __expf(a);
        P[(size_t)row * NR + col] = f2bf(p);
        ps[mi][r] += p;
      }
  }
#pragma unroll
  for (int mi = 0; mi < 4; ++mi)
#pragma unroll
    for (int r = 0; r < 4; ++r) {
      float s = ps[mi][r];
      s += __shfl_xor(s, 1); s += __shfl_xor(s, 2);
      s += __shfl_xor(s, 4); s += __shfl_xor(s, 8);
      if ((lane & 15) == 0) {
        int row = m0 + wr * 64 + mi * 16 + (lane >> 4) * 4 + r;
        psum[(size_t)(blockIdx.x * 2 + wc) * NR + row] = s;
      }
    }
}

// ---------------- K3: rinv + activity bitmasks per 16-row group -----------
// actbits[g*2+h]: bit kt set iff any row in group g has chunk (h*64+kt)
// relative mass > ACT_THR. Group = 16 consecutive rows.
__global__ void k_rowsum(const float* __restrict__ psum,
                         float* __restrict__ rinv,
                         u64* __restrict__ actbits) {
  int i = blockIdx.x * 256 + threadIdx.x;  // row, 8192 threads
  float s = 0.f;
  for (int t = 0; t < 128; ++t) s += psum[(size_t)t * NR + i];
  float inv = (s > 0.f) ? 1.f / s : 0.f;
  rinv[i] = inv;
  u64 b0 = 0, b1 = 0;
  for (int t = 0; t < 64; ++t)
    if (psum[(size_t)t * NR + i] * inv > ACT_THR) b0 |= (1ull << t);
  for (int t = 0; t < 64; ++t)
    if (psum[(size_t)(t + 64) * NR + i] * inv > ACT_THR) b1 |= (1ull << t);
  // OR across the 16-row group (rows are consecutive lanes)
#pragma unroll
  for (int d = 1; d < 16; d <<= 1) {
    b0 |= __shfl_xor(b0, d);
    b1 |= __shfl_xor(b1, d);
  }
  if ((threadIdx.x & 15) == 0) {
    actbits[(size_t)(i >> 4) * 2 + 0] = b0;
    actbits[(size_t)(i >> 4) * 2 + 1] = b1;
  }
}

// ---------------- K4: O_partial = P @ V (split-K=2, sparse-skip) ----------
// Per kt-chunk: skip A(P)-staging sub-chunks and MFMAs for dead 16-row
// groups (wave-uniform branches; producer and consumer gated by same bit).
__global__ __launch_bounds__(256, 4) void k_pv(
    const u16* __restrict__ P, const u16* __restrict__ vt,
    const u64* __restrict__ actbits,
    u16* __restrict__ Opart) {
  __shared__ __align__(16) u16 sA[128 * 64], sB[128 * 64];
  const int m0 = blockIdx.y * 128, n0 = blockIdx.x * 128;
  const int z = blockIdx.z;
  const int lane = threadIdx.x & 63;
  const int wid = threadIdx.x >> 6;
  const int wr = wid >> 1, wc = wid & 1;

  f32x4 acc[4][4] = {};
  const bool isA = wid < 2;
  const u16* gS = isA ? P : vt;
  u16* Dst = isA ? sA : sB;
  const int gb = isA ? m0 : n0;
  const int rbase = (wid & 1) * 64;

  // all 8 groups' masks for this z (wave-uniform loads)
  u64 actg[8];
#pragma unroll
  for (int j = 0; j < 8; ++j)
    actg[j] = actbits[(size_t)((m0 >> 4) + j) * 2 + z];

  for (int kt = 0; kt < 64; ++kt) {
    int kg = z * 4096 + kt * 64;
    if (isA) {
#pragma unroll
      for (int c = 0; c < 8; ++c) {
        if (!((actg[(rbase >> 4) + (c >> 1)] >> kt) & 1)) continue;
        int row = rbase + c * 8 + (lane >> 3);
        int srck = kg + (((lane & 7) ^ (row & 7)) << 3);
        load_lds16(gS + (size_t)(gb + row) * NR + srck,
                   (char*)Dst + (size_t)(rbase + c * 8) * 128);
      }
    } else {
#pragma unroll
      for (int c = 0; c < 8; ++c) {
        int row = rbase + c * 8 + (lane >> 3);
        int srck = kg + (((lane & 7) ^ (row & 7)) << 3);
        load_lds16(gS + (size_t)(gb + row) * NR + srck,
                   (char*)Dst + (size_t)(rbase + c * 8) * 128);
      }
    }
    __syncthreads();
#pragma unroll
    for (int dt = 0; dt < 2; ++dt) {
      short8 a[4], b[4];
      int kb = dt * 64 + ((lane >> 4) << 4);
#pragma unroll
      for (int t = 0; t < 4; ++t) {
        int rb = wc * 64 + t * 16 + (lane & 15);
        b[t] = *(const short8*)((const char*)sB + rb * 128 + (kb ^ ((rb & 7) << 4)));
      }
#pragma unroll
      for (int mi = 0; mi < 4; ++mi) {
        if (!((actg[wr * 4 + mi] >> kt) & 1)) continue;
        int ra = wr * 64 + mi * 16 + (lane & 15);
        a[mi] = *(const short8*)((const char*)sA + ra * 128 + (kb ^ ((ra & 7) << 4)));
#pragma unroll
        for (int ni = 0; ni < 4; ++ni)
          acc[mi][ni] = __builtin_amdgcn_mfma_f32_16x16x32_bf16(a[mi], b[ni], acc[mi][ni], 0, 0, 0);
      }
    }
    __syncthreads();
  }
#pragma unroll
  for (int ni = 0; ni < 4; ++ni) {
    int col = n0 + wc * 64 + ni * 16 + (lane & 15);
#pragma unroll
    for (int mi = 0; mi < 4; ++mi)
#pragma unroll
      for (int r = 0; r < 4; ++r) {
        int row = m0 + wr * 64 + mi * 16 + (lane >> 4) * 4 + r;
        Opart[((size_t)z * NR + row) * DI + col] = f2bf(acc[mi][ni][r]);
      }
  }
}

// ---------------- K5: h = x + (Op0+Op1)*rinv; LayerNorm; col partials -----
__global__ __launch_bounds__(256) void k_ln(const u16* __restrict__ Opart,
                                            const float* __restrict__ x,
                                            const float* __restrict__ rinv,
                                            const float* __restrict__ gamma,
                                            const float* __restrict__ beta,
                                            float* __restrict__ part) {
  const int lane = threadIdx.x & 63;
  const int w = threadIdx.x >> 6;
  float4 g0 = *(const float4*)(gamma + lane * 8);
  float4 g1 = *(const float4*)(gamma + lane * 8 + 4);
  float4 b0 = *(const float4*)(beta + lane * 8);
  float4 b1 = *(const float4*)(beta + lane * 8 + 4);
  float ga[8] = {g0.x, g0.y, g0.z, g0.w, g1.x, g1.y, g1.z, g1.w};
  float be[8] = {b0.x, b0.y, b0.z, b0.w, b1.x, b1.y, b1.z, b1.w};
  float colacc[8] = {0, 0, 0, 0, 0, 0, 0, 0};
  for (int it = 0; it < 32; ++it) {
    int row = blockIdx.x * 128 + it * 4 + w;
    float rv = rinv[row];
    const u16* o0r = Opart + (size_t)row * DI + lane * 8;
    const u16* o1r = o0r + (size_t)NR * DI;
    const float* xr = x + (size_t)row * DI + lane * 8;
    short8 s0 = *(const short8*)o0r;
    short8 s1 = *(const short8*)o1r;
    float4 xa = *(const float4*)xr;
    float4 xb = *(const float4*)(xr + 4);
    float xv[8] = {xa.x, xa.y, xa.z, xa.w, xb.x, xb.y, xb.z, xb.w};
    float v[8];
#pragma unroll
    for (int j = 0; j < 8; ++j)
      v[j] = (bf2f((u16)s0[j]) + bf2f((u16)s1[j])) * rv + xv[j];
    float s1s = 0.f, s2s = 0.f;
#pragma unroll
    for (int j = 0; j < 8; ++j) { s1s += v[j]; s2s += v[j] * v[j]; }
#pragma unroll
    for (int m = 1; m < 64; m <<= 1) { s1s += __shfl_xor(s1s, m); s2s += __shfl_xor(s2s, m); }
    float mean = s1s * (1.f / DI);
    float var = fmaxf(s2s * (1.f / DI) - mean * mean, 0.f);
    float rstd = rsqrtf(var + 1e-5f);
#pragma unroll
    for (int j = 0; j < 8; ++j) colacc[j] += (v[j] - mean) * rstd * ga[j] + be[j];
  }
  __shared__ float red[4][DI];
#pragma unroll
  for (int j = 0; j < 8; ++j) red[w][lane * 8 + j] = colacc[j];
  __syncthreads();
  for (int d = threadIdx.x; d < DI; d += 256)
    part[(size_t)blockIdx.x * DI + d] = red[0][d] + red[1][d] + red[2][d] + red[3][d];
}

// ---------------- K6: final mean ----------------
__global__ void k_final(const float* __restrict__ part, float* __restrict__ out) {
  int d = threadIdx.x;  // 512 threads
  float s = 0.f;
  for (int t = 0; t < 64; ++t) s += part[(size_t)t * DI + d];
  out[d] = s * (1.f / NR);
}

extern "C" void kernel_launch(void* const* d_in, const int* in_sizes, int n_in,
                              void* d_out, int out_size, void* d_ws, size_t ws_size,
                              hipStream_t stream) {
  (void)in_sizes; (void)n_in; (void)out_size; (void)ws_size;
  const float* x = (const float*)d_in[0];
  const float* wq = (const float*)d_in[1];
  const float* bq = (const float*)d_in[2];
  const float* wk = (const float*)d_in[3];
  const float* bk = (const float*)d_in[4];
  const float* wv = (const float*)d_in[5];
  const float* bv = (const float*)d_in[6];
  const float* gamma = (const float*)d_in[7];
  const float* beta = (const float*)d_in[8];
  float* out = (float*)d_out;

  char* cur = (char*)d_ws;
  auto alloc = [&](size_t bytes) -> char* {
    char* p = cur;
    cur += (bytes + 255) & ~(size_t)255;
    return p;
  };
  u16* xhi = (u16*)alloc((size_t)NR * DI * 2);
  u16* whi = (u16*)alloc((size_t)3 * DI * DI * 2);
  u16* qhi = (u16*)alloc((size_t)NR * DI * 2);
  u16* khi = (u16*)alloc((size_t)NR * DI * 2);
  u16* vt = (u16*)alloc((size_t)DI * NR * 2);
  float* qnp = (float*)alloc((size_t)8 * NR * 4);
  float* cvec = (float*)alloc((size_t)NR * 4);
  float* psum = (float*)alloc((size_t)128 * NR * 4);
  float* rinv = (float*)alloc((size_t)NR * 4);
  u64* actbits = (u64*)alloc((size_t)512 * 2 * 8);
  u16* P = (u16*)alloc((size_t)NR * NR * 2);
  u16* Opart = (u16*)alloc((size_t)2 * NR * DI * 2);
  float* part = (float*)alloc((size_t)64 * DI * 4);

  k_prep<<<1024, 256, 0, stream>>>(x, wq, wk, wv, xhi, whi);
  k_qkv<<<dim3(4, 64, 3), 256, 0, stream>>>(xhi, whi, bq, bk, bv,
                                            qhi, khi, vt, qnp);
  k_cvec<<<32, 256, 0, stream>>>(qnp, cvec);
  k_scores<<<dim3(64, 64), 256, 0, stream>>>(qhi, khi, cvec, P, psum);
  k_rowsum<<<32, 256, 0, stream>>>(psum, rinv, actbits);
  k_pv<<<dim3(4, 64, 2), 256, 0, stream>>>(P, vt, actbits, Opart);
  k_ln<<<64, 256, 0, stream>>>(Opart, x, rinv, gamma, beta, part);
  k_final<<<1, 512, 0, stream>>>(part, out);
}

// Round 13
// 256.114 us; speedup vs baseline: 1.4149x; 1.4149x over previous
//
#include <hip/hip_runtime.h>
#include <stdint.h>

// Fused single-head attention + LN + mean-pool, MI355X (gfx950).
// Precision: 1-pass bf16 MFMA everywhere (QKV, QK^T, P@V); absmax floor
// ~6.7e-4 (P/V bf16 quant), validated r2-r12. Opart bf16 x4 split-K slabs.
// Softmax shift c_i = 5|q_i|+10 (cancels exactly; tail-safe).
// Schedule: fat 1-phase, 128^2 tiles. Lessons: 256-wide tiles thrash L2
// (r6/r10); XCD swizzle breaks B-panel L2 slicing (r7); shallow 2-phase
// loses (r3); conditional staging breaks load batching (r12).
// Round 13: k_pv split-K=4 (grid 1024 blocks -> 4 blocks/CU; r11's 19%
// occupancy was grid-capped at 512 blocks).

#define NR 8192
#define DI 512

typedef float f32x4 __attribute__((ext_vector_type(4)));
typedef short short8 __attribute__((ext_vector_type(8)));
typedef unsigned short u16;

__device__ __forceinline__ u16 f2bf(float f) {
  union { float f; unsigned u; } v; v.f = f;
  unsigned u = v.u;
  return (u16)((u + 0x7FFFu + ((u >> 16) & 1u)) >> 16);  // RNE
}
__device__ __forceinline__ float bf2f(u16 b) {
  union { unsigned u; float f; } v; v.u = ((unsigned)b) << 16;
  return v.f;
}

__device__ __forceinline__ void load_lds16(const void* g, void* l) {
  __builtin_amdgcn_global_load_lds(
      (const __attribute__((address_space(1))) unsigned int*)g,
      (__attribute__((address_space(3))) unsigned int*)l, 16, 0, 0);
}

// ---------------- K0: convert inputs to bf16 ----------------
__global__ void k_prep(const float* __restrict__ x,
                       const float* __restrict__ wq,
                       const float* __restrict__ wk,
                       const float* __restrict__ wv,
                       u16* __restrict__ xhi, u16* __restrict__ whi) {
  int tid = blockIdx.x * 256 + threadIdx.x;
  int nth = gridDim.x * 256;
  const float4* x4 = (const float4*)x;
  ushort4* xh4 = (ushort4*)xhi;
  for (int i = tid; i < NR * DI / 4; i += nth) {
    float4 v = x4[i];
    ushort4 h;
    h.x = f2bf(v.x); h.y = f2bf(v.y); h.z = f2bf(v.z); h.w = f2bf(v.w);
    xh4[i] = h;
  }
  ushort4* wh4 = (ushort4*)whi;
  const int wq4 = DI * DI / 4;
  for (int i = tid; i < 3 * wq4; i += nth) {
    int z = i / wq4, j = i - z * wq4;
    const float4* src = (const float4*)(z == 0 ? wq : z == 1 ? wk : wv);
    float4 v = src[j];
    ushort4 h;
    h.x = f2bf(v.x); h.y = f2bf(v.y); h.z = f2bf(v.z); h.w = f2bf(v.w);
    wh4[i] = h;
  }
}

// ---------------- K1: q/k/v = xhi @ Whi^T + b (z = 0/1/2) -----------------
__global__ __launch_bounds__(256, 4) void k_qkv(
    const u16* __restrict__ xhi, const u16* __restrict__ whi,
    const float* __restrict__ bq, const float* __restrict__ bk,
    const float* __restrict__ bv,
    u16* __restrict__ qhi, u16* __restrict__ khi,
    u16* __restrict__ vt, float* __restrict__ qnp) {
  __shared__ __align__(16) u16 sA[128 * 64], sB[128 * 64];
  const int z = blockIdx.z;
  const int m0 = blockIdx.y * 128, n0 = blockIdx.x * 128;
  const int lane = threadIdx.x & 63, wid = threadIdx.x >> 6;
  const int wr = wid >> 1, wc = wid & 1;
  const u16* Wh = whi + (size_t)z * DI * DI;
  f32x4 acc[4][4] = {};
  const bool isA = wid < 2;
  const u16* gS = isA ? xhi : Wh;
  u16* Dst = isA ? sA : sB;
  const int gb = isA ? m0 : n0;
  const int rbase = (wid & 1) * 64;

  for (int kt = 0; kt < 8; ++kt) {
#pragma unroll
    for (int c = 0; c < 8; ++c) {
      int row = rbase + c * 8 + (lane >> 3);
      int srck = kt * 64 + (((lane & 7) ^ (row & 7)) << 3);
      load_lds16(gS + (size_t)(gb + row) * DI + srck,
                 (char*)Dst + (size_t)(rbase + c * 8) * 128);
    }
    __syncthreads();
#pragma unroll
    for (int dt = 0; dt < 2; ++dt) {
      short8 a[4], b[4];
      int kb = dt * 64 + ((lane >> 4) << 4);
#pragma unroll
      for (int t = 0; t < 4; ++t) {
        int ra = wr * 64 + t * 16 + (lane & 15);
        a[t] = *(const short8*)((const char*)sA + ra * 128 + (kb ^ ((ra & 7) << 4)));
        int rb = wc * 64 + t * 16 + (lane & 15);
        b[t] = *(const short8*)((const char*)sB + rb * 128 + (kb ^ ((rb & 7) << 4)));
      }
#pragma unroll
      for (int mi = 0; mi < 4; ++mi)
#pragma unroll
        for (int ni = 0; ni < 4; ++ni)
          acc[mi][ni] = __builtin_amdgcn_mfma_f32_16x16x32_bf16(a[mi], b[ni], acc[mi][ni], 0, 0, 0);
    }
    __syncthreads();
  }

  const float* bias = (z == 0) ? bq : (z == 1) ? bk : bv;
  if (z < 2) {
    u16* oh = (z == 0) ? qhi : khi;
    float rowsq[4][4] = {};
#pragma unroll
    for (int ni = 0; ni < 4; ++ni) {
      int col = n0 + wc * 64 + ni * 16 + (lane & 15);
      float b = bias[col];
#pragma unroll
      for (int mi = 0; mi < 4; ++mi)
#pragma unroll
        for (int r = 0; r < 4; ++r) {
          int row = m0 + wr * 64 + mi * 16 + (lane >> 4) * 4 + r;
          float v = acc[mi][ni][r] + b;
          oh[(size_t)row * DI + col] = f2bf(v);
          if (z == 0) rowsq[mi][r] += v * v;
        }
    }
    if (z == 0) {
#pragma unroll
      for (int mi = 0; mi < 4; ++mi)
#pragma unroll
        for (int r = 0; r < 4; ++r) {
          float s = rowsq[mi][r];
          s += __shfl_xor(s, 1); s += __shfl_xor(s, 2);
          s += __shfl_xor(s, 4); s += __shfl_xor(s, 8);
          if ((lane & 15) == 0) {
            int row = m0 + wr * 64 + mi * 16 + (lane >> 4) * 4 + r;
            qnp[(size_t)(blockIdx.x * 2 + wc) * NR + row] = s;
          }
        }
    }
  } else {
    // v: store transposed vt[d][i] bf16, packing 4 consecutive rows per lane
#pragma unroll
    for (int ni = 0; ni < 4; ++ni) {
      int col = n0 + wc * 64 + ni * 16 + (lane & 15);
      float b = bias[col];
#pragma unroll
      for (int mi = 0; mi < 4; ++mi) {
        int rowb = m0 + wr * 64 + mi * 16 + (lane >> 4) * 4;
        ushort4 pk;
        pk.x = f2bf(acc[mi][ni][0] + b);
        pk.y = f2bf(acc[mi][ni][1] + b);
        pk.z = f2bf(acc[mi][ni][2] + b);
        pk.w = f2bf(acc[mi][ni][3] + b);
        *(ushort4*)(vt + (size_t)col * NR + rowb) = pk;
      }
    }
  }
}

// ---------------- K1b: c_i = 5*|q_i| + 10 ----------------
__global__ void k_cvec(const float* __restrict__ qnp, float* __restrict__ cvec) {
  int i = blockIdx.x * 256 + threadIdx.x;  // grid 32 x 256 = 8192
  float s = 0.f;
#pragma unroll
  for (int t = 0; t < 8; ++t) s += qnp[(size_t)t * NR + i];
  cvec[i] = 5.0f * sqrtf(s) + 10.f;
}

// ---------------- K2: P = exp(qhi·khi - c_row), partial row sums ----------
// 1-pass, 32 KB LDS. Fat 1-phase. Default dispatch (no swizzle).
__global__ __launch_bounds__(256, 4) void k_scores(
    const u16* __restrict__ qhi, const u16* __restrict__ khi,
    const float* __restrict__ cvec,
    u16* __restrict__ P, float* __restrict__ psum) {
  __shared__ __align__(16) u16 sA[128 * 64], sB[128 * 64];
  const int m0 = blockIdx.y * 128, n0 = blockIdx.x * 128;
  const int lane = threadIdx.x & 63, wid = threadIdx.x >> 6;
  const int wr = wid >> 1, wc = wid & 1;
  f32x4 acc[4][4] = {};
  const bool isA = wid < 2;
  const u16* gS = isA ? qhi : khi;
  u16* Dst = isA ? sA : sB;
  const int gb = isA ? m0 : n0;
  const int rbase = (wid & 1) * 64;

  for (int kt = 0; kt < 8; ++kt) {
#pragma unroll
    for (int c = 0; c < 8; ++c) {
      int row = rbase + c * 8 + (lane >> 3);
      int srck = kt * 64 + (((lane & 7) ^ (row & 7)) << 3);
      load_lds16(gS + (size_t)(gb + row) * DI + srck,
                 (char*)Dst + (size_t)(rbase + c * 8) * 128);
    }
    __syncthreads();
#pragma unroll
    for (int dt = 0; dt < 2; ++dt) {
      short8 a[4], b[4];
      int kb = dt * 64 + ((lane >> 4) << 4);
#pragma unroll
      for (int t = 0; t < 4; ++t) {
        int ra = wr * 64 + t * 16 + (lane & 15);
        a[t] = *(const short8*)((const char*)sA + ra * 128 + (kb ^ ((ra & 7) << 4)));
        int rb = wc * 64 + t * 16 + (lane & 15);
        b[t] = *(const short8*)((const char*)sB + rb * 128 + (kb ^ ((rb & 7) << 4)));
      }
#pragma unroll
      for (int mi = 0; mi < 4; ++mi)
#pragma unroll
        for (int ni = 0; ni < 4; ++ni)
          acc[mi][ni] = __builtin_amdgcn_mfma_f32_16x16x32_bf16(a[mi], b[ni], acc[mi][ni], 0, 0, 0);
    }
    __syncthreads();
  }

  float cr[4][4];
#pragma unroll
  for (int mi = 0; mi < 4; ++mi)
#pragma unroll
    for (int r = 0; r < 4; ++r)
      cr[mi][r] = cvec[m0 + wr * 64 + mi * 16 + (lane >> 4) * 4 + r];

  float ps[4][4] = {};
#pragma unroll
  for (int ni = 0; ni < 4; ++ni) {
    int col = n0 + wc * 64 + ni * 16 + (lane & 15);
#pragma unroll
    for (int mi = 0; mi < 4; ++mi)
#pragma unroll
      for (int r = 0; r < 4; ++r) {
        int row = m0 + wr * 64 + mi * 16 + (lane >> 4) * 4 + r;
        float a = fminf(acc[mi][ni][r] - cr[mi][r], 60.f);  // overflow guard
        float p = __expf(a);
        P[(size_t)row * NR + col] = f2bf(p);
        ps[mi][r] += p;
      }
  }
#pragma unroll
  for (int mi = 0; mi < 4; ++mi)
#pragma unroll
    for (int r = 0; r < 4; ++r) {
      float s = ps[mi][r];
      s += __shfl_xor(s, 1); s += __shfl_xor(s, 2);
      s += __shfl_xor(s, 4); s += __shfl_xor(s, 8);
      if ((lane & 15) == 0) {
        int row = m0 + wr * 64 + mi * 16 + (lane >> 4) * 4 + r;
        psum[(size_t)(blockIdx.x * 2 + wc) * NR + row] = s;
      }
    }
}

// ---------------- K3: row sums -> 1/sum (guarded) ----------------
__global__ void k_rowsum(const float* __restrict__ psum, float* __restrict__ rinv) {
  int i = blockIdx.x * 256 + threadIdx.x;  // 8192 threads
  float s = 0.f;
  for (int t = 0; t < 128; ++t) s += psum[(size_t)t * NR + i];
  rinv[i] = (s > 0.f) ? 1.f / s : 0.f;
}

// ---------------- K4: O_partial = P @ V (split-K = 4, 1-phase, bf16 out) --
// Grid (4, 64, 4) = 1024 blocks -> 4 blocks/CU (r11 was grid-capped at 2).
// Each z covers 2048 k = 32 kt-steps of 64.
__global__ __launch_bounds__(256, 4) void k_pv(
    const u16* __restrict__ P, const u16* __restrict__ vt,
    u16* __restrict__ Opart) {
  __shared__ __align__(16) u16 sA[128 * 64], sB[128 * 64];
  const int m0 = blockIdx.y * 128, n0 = blockIdx.x * 128;
  const int z = blockIdx.z;
  const int lane = threadIdx.x & 63;
  const int wid = threadIdx.x >> 6;
  const int wr = wid >> 1, wc = wid & 1;

  f32x4 acc[4][4] = {};
  const bool isA = wid < 2;
  const u16* gS = isA ? P : vt;
  u16* Dst = isA ? sA : sB;
  const int gb = isA ? m0 : n0;
  const int rbase = (wid & 1) * 64;

  for (int kt = 0; kt < 32; ++kt) {
    int kg = z * 2048 + kt * 64;
#pragma unroll
    for (int c = 0; c < 8; ++c) {
      int row = rbase + c * 8 + (lane >> 3);
      int srck = kg + (((lane & 7) ^ (row & 7)) << 3);
      load_lds16(gS + (size_t)(gb + row) * NR + srck,
                 (char*)Dst + (size_t)(rbase + c * 8) * 128);
    }
    __syncthreads();
#pragma unroll
    for (int dt = 0; dt < 2; ++dt) {
      short8 a[4], b[4];
      int kb = dt * 64 + ((lane >> 4) << 4);
#pragma unroll
      for (int t = 0; t < 4; ++t) {
        int ra = wr * 64 + t * 16 + (lane & 15);
        a[t] = *(const short8*)((const char*)sA + ra * 128 + (kb ^ ((ra & 7) << 4)));
        int rb = wc * 64 + t * 16 + (lane & 15);
        b[t] = *(const short8*)((const char*)sB + rb * 128 + (kb ^ ((rb & 7) << 4)));
      }
#pragma unroll
      for (int mi = 0; mi < 4; ++mi)
#pragma unroll
        for (int ni = 0; ni < 4; ++ni)
          acc[mi][ni] = __builtin_amdgcn_mfma_f32_16x16x32_bf16(a[mi], b[ni], acc[mi][ni], 0, 0, 0);
    }
    __syncthreads();
  }
#pragma unroll
  for (int ni = 0; ni < 4; ++ni) {
    int col = n0 + wc * 64 + ni * 16 + (lane & 15);
#pragma unroll
    for (int mi = 0; mi < 4; ++mi)
#pragma unroll
      for (int r = 0; r < 4; ++r) {
        int row = m0 + wr * 64 + mi * 16 + (lane >> 4) * 4 + r;
        Opart[((size_t)z * NR + row) * DI + col] = f2bf(acc[mi][ni][r]);
      }
  }
}

// ---------------- K5: h = x + (sum Op)*rinv; LayerNorm; col partials ------
__global__ __launch_bounds__(256) void k_ln(const u16* __restrict__ Opart,
                                            const float* __restrict__ x,
                                            const float* __restrict__ rinv,
                                            const float* __restrict__ gamma,
                                            const float* __restrict__ beta,
                                            float* __restrict__ part) {
  const int lane = threadIdx.x & 63;
  const int w = threadIdx.x >> 6;
  float4 g0 = *(const float4*)(gamma + lane * 8);
  float4 g1 = *(const float4*)(gamma + lane * 8 + 4);
  float4 b0 = *(const float4*)(beta + lane * 8);
  float4 b1 = *(const float4*)(beta + lane * 8 + 4);
  float ga[8] = {g0.x, g0.y, g0.z, g0.w, g1.x, g1.y, g1.z, g1.w};
  float be[8] = {b0.x, b0.y, b0.z, b0.w, b1.x, b1.y, b1.z, b1.w};
  float colacc[8] = {0, 0, 0, 0, 0, 0, 0, 0};
  const size_t slab = (size_t)NR * DI;
  for (int it = 0; it < 32; ++it) {
    int row = blockIdx.x * 128 + it * 4 + w;
    float rv = rinv[row];
    const u16* ob = Opart + (size_t)row * DI + lane * 8;
    const float* xr = x + (size_t)row * DI + lane * 8;
    short8 s0 = *(const short8*)(ob);
    short8 s1 = *(const short8*)(ob + slab);
    short8 s2 = *(const short8*)(ob + 2 * slab);
    short8 s3 = *(const short8*)(ob + 3 * slab);
    float4 xa = *(const float4*)xr;
    float4 xb = *(const float4*)(xr + 4);
    float xv[8] = {xa.x, xa.y, xa.z, xa.w, xb.x, xb.y, xb.z, xb.w};
    float v[8];
#pragma unroll
    for (int j = 0; j < 8; ++j)
      v[j] = (bf2f((u16)s0[j]) + bf2f((u16)s1[j]) +
              bf2f((u16)s2[j]) + bf2f((u16)s3[j])) * rv + xv[j];
    float s1s = 0.f, s2s = 0.f;
#pragma unroll
    for (int j = 0; j < 8; ++j) { s1s += v[j]; s2s += v[j] * v[j]; }
#pragma unroll
    for (int m = 1; m < 64; m <<= 1) { s1s += __shfl_xor(s1s, m); s2s += __shfl_xor(s2s, m); }
    float mean = s1s * (1.f / DI);
    float var = fmaxf(s2s * (1.f / DI) - mean * mean, 0.f);
    float rstd = rsqrtf(var + 1e-5f);
#pragma unroll
    for (int j = 0; j < 8; ++j) colacc[j] += (v[j] - mean) * rstd * ga[j] + be[j];
  }
  __shared__ float red[4][DI];
#pragma unroll
  for (int j = 0; j < 8; ++j) red[w][lane * 8 + j] = colacc[j];
  __syncthreads();
  for (int d = threadIdx.x; d < DI; d += 256)
    part[(size_t)blockIdx.x * DI + d] = red[0][d] + red[1][d] + red[2][d] + red[3][d];
}

// ---------------- K6: final mean ----------------
__global__ void k_final(const float* __restrict__ part, float* __restrict__ out) {
  int d = threadIdx.x;  // 512 threads
  float s = 0.f;
  for (int t = 0; t < 64; ++t) s += part[(size_t)t * DI + d];
  out[d] = s * (1.f / NR);
}

extern "C" void kernel_launch(void* const* d_in, const int* in_sizes, int n_in,
                              void* d_out, int out_size, void* d_ws, size_t ws_size,
                              hipStream_t stream) {
  (void)in_sizes; (void)n_in; (void)out_size; (void)ws_size;
  const float* x = (const float*)d_in[0];
  const float* wq = (const float*)d_in[1];
  const float* bq = (const float*)d_in[2];
  const float* wk = (const float*)d_in[3];
  const float* bk = (const float*)d_in[4];
  const float* wv = (const float*)d_in[5];
  const float* bv = (const float*)d_in[6];
  const float* gamma = (const float*)d_in[7];
  const float* beta = (const float*)d_in[8];
  float* out = (float*)d_out;

  char* cur = (char*)d_ws;
  auto alloc = [&](size_t bytes) -> char* {
    char* p = cur;
    cur += (bytes + 255) & ~(size_t)255;
    return p;
  };
  u16* xhi = (u16*)alloc((size_t)NR * DI * 2);
  u16* whi = (u16*)alloc((size_t)3 * DI * DI * 2);
  u16* qhi = (u16*)alloc((size_t)NR * DI * 2);
  u16* khi = (u16*)alloc((size_t)NR * DI * 2);
  u16* vt = (u16*)alloc((size_t)DI * NR * 2);
  float* qnp = (float*)alloc((size_t)8 * NR * 4);
  float* cvec = (float*)alloc((size_t)NR * 4);
  float* psum = (float*)alloc((size_t)128 * NR * 4);
  float* rinv = (float*)alloc((size_t)NR * 4);
  u16* P = (u16*)alloc((size_t)NR * NR * 2);
  u16* Opart = (u16*)alloc((size_t)4 * NR * DI * 2);
  float* part = (float*)alloc((size_t)64 * DI * 4);

  k_prep<<<1024, 256, 0, stream>>>(x, wq, wk, wv, xhi, whi);
  k_qkv<<<dim3(4, 64, 3), 256, 0, stream>>>(xhi, whi, bq, bk, bv,
                                            qhi, khi, vt, qnp);
  k_cvec<<<32, 256, 0, stream>>>(qnp, cvec);
  k_scores<<<dim3(64, 64), 256, 0, stream>>>(qhi, khi, cvec, P, psum);
  k_rowsum<<<32, 256, 0, stream>>>(psum, rinv);
  k_pv<<<dim3(4, 64, 4), 256, 0, stream>>>(P, vt, Opart);
  k_ln<<<64, 256, 0, stream>>>(Opart, x, rinv, gamma, beta, part);
  k_final<<<1, 512, 0, stream>>>(part, out);
}

// Round 14
// 236.422 us; speedup vs baseline: 1.5328x; 1.0833x over previous
//
#include <hip/hip_runtime.h>
#include <stdint.h>

// Fused single-head attention + LN + mean-pool, MI355X (gfx950).
// Precision: 1-pass bf16 MFMA everywhere; absmax floor ~7e-4 (P/V bf16
// quant), validated r2-r13. Opart bf16 x4 split-K slabs.
// Softmax shift c_i = 5|q_i|+10 (cancels exactly; tail-safe).
// Schedule: fat 1-phase, 128^2 tiles for k_qkv/k_scores.
// Lessons: per-block-distinct 256-wide B panels thrash L2 (r6/r10);
// XCD swizzle breaks natural B-panel L2 slicing (r7); shallow 2-phase
// loses (r3); conditional staging breaks load batching (r12); k_pv is
// FETCH-bound on P re-reads, occupancy irrelevant (r13).
// Round 14: k_pv nx=1 — one block per (m-tile, z) computes ALL 512 output
// cols; P streamed exactly once (134 MB floor); vt B-tile (64 KB) is the
// SAME data for every block -> L2-resident everywhere.

#define NR 8192
#define DI 512

typedef float f32x4 __attribute__((ext_vector_type(4)));
typedef short short8 __attribute__((ext_vector_type(8)));
typedef unsigned short u16;

__device__ __forceinline__ u16 f2bf(float f) {
  union { float f; unsigned u; } v; v.f = f;
  unsigned u = v.u;
  return (u16)((u + 0x7FFFu + ((u >> 16) & 1u)) >> 16);  // RNE
}
__device__ __forceinline__ float bf2f(u16 b) {
  union { unsigned u; float f; } v; v.u = ((unsigned)b) << 16;
  return v.f;
}

__device__ __forceinline__ void load_lds16(const void* g, void* l) {
  __builtin_amdgcn_global_load_lds(
      (const __attribute__((address_space(1))) unsigned int*)g,
      (__attribute__((address_space(3))) unsigned int*)l, 16, 0, 0);
}

// ---------------- K0: convert inputs to bf16 ----------------
__global__ void k_prep(const float* __restrict__ x,
                       const float* __restrict__ wq,
                       const float* __restrict__ wk,
                       const float* __restrict__ wv,
                       u16* __restrict__ xhi, u16* __restrict__ whi) {
  int tid = blockIdx.x * 256 + threadIdx.x;
  int nth = gridDim.x * 256;
  const float4* x4 = (const float4*)x;
  ushort4* xh4 = (ushort4*)xhi;
  for (int i = tid; i < NR * DI / 4; i += nth) {
    float4 v = x4[i];
    ushort4 h;
    h.x = f2bf(v.x); h.y = f2bf(v.y); h.z = f2bf(v.z); h.w = f2bf(v.w);
    xh4[i] = h;
  }
  ushort4* wh4 = (ushort4*)whi;
  const int wq4 = DI * DI / 4;
  for (int i = tid; i < 3 * wq4; i += nth) {
    int z = i / wq4, j = i - z * wq4;
    const float4* src = (const float4*)(z == 0 ? wq : z == 1 ? wk : wv);
    float4 v = src[j];
    ushort4 h;
    h.x = f2bf(v.x); h.y = f2bf(v.y); h.z = f2bf(v.z); h.w = f2bf(v.w);
    wh4[i] = h;
  }
}

// ---------------- K1: q/k/v = xhi @ Whi^T + b (z = 0/1/2) -----------------
__global__ __launch_bounds__(256, 4) void k_qkv(
    const u16* __restrict__ xhi, const u16* __restrict__ whi,
    const float* __restrict__ bq, const float* __restrict__ bk,
    const float* __restrict__ bv,
    u16* __restrict__ qhi, u16* __restrict__ khi,
    u16* __restrict__ vt, float* __restrict__ qnp) {
  __shared__ __align__(16) u16 sA[128 * 64], sB[128 * 64];
  const int z = blockIdx.z;
  const int m0 = blockIdx.y * 128, n0 = blockIdx.x * 128;
  const int lane = threadIdx.x & 63, wid = threadIdx.x >> 6;
  const int wr = wid >> 1, wc = wid & 1;
  const u16* Wh = whi + (size_t)z * DI * DI;
  f32x4 acc[4][4] = {};
  const bool isA = wid < 2;
  const u16* gS = isA ? xhi : Wh;
  u16* Dst = isA ? sA : sB;
  const int gb = isA ? m0 : n0;
  const int rbase = (wid & 1) * 64;

  for (int kt = 0; kt < 8; ++kt) {
#pragma unroll
    for (int c = 0; c < 8; ++c) {
      int row = rbase + c * 8 + (lane >> 3);
      int srck = kt * 64 + (((lane & 7) ^ (row & 7)) << 3);
      load_lds16(gS + (size_t)(gb + row) * DI + srck,
                 (char*)Dst + (size_t)(rbase + c * 8) * 128);
    }
    __syncthreads();
#pragma unroll
    for (int dt = 0; dt < 2; ++dt) {
      short8 a[4], b[4];
      int kb = dt * 64 + ((lane >> 4) << 4);
#pragma unroll
      for (int t = 0; t < 4; ++t) {
        int ra = wr * 64 + t * 16 + (lane & 15);
        a[t] = *(const short8*)((const char*)sA + ra * 128 + (kb ^ ((ra & 7) << 4)));
        int rb = wc * 64 + t * 16 + (lane & 15);
        b[t] = *(const short8*)((const char*)sB + rb * 128 + (kb ^ ((rb & 7) << 4)));
      }
#pragma unroll
      for (int mi = 0; mi < 4; ++mi)
#pragma unroll
        for (int ni = 0; ni < 4; ++ni)
          acc[mi][ni] = __builtin_amdgcn_mfma_f32_16x16x32_bf16(a[mi], b[ni], acc[mi][ni], 0, 0, 0);
    }
    __syncthreads();
  }

  const float* bias = (z == 0) ? bq : (z == 1) ? bk : bv;
  if (z < 2) {
    u16* oh = (z == 0) ? qhi : khi;
    float rowsq[4][4] = {};
#pragma unroll
    for (int ni = 0; ni < 4; ++ni) {
      int col = n0 + wc * 64 + ni * 16 + (lane & 15);
      float b = bias[col];
#pragma unroll
      for (int mi = 0; mi < 4; ++mi)
#pragma unroll
        for (int r = 0; r < 4; ++r) {
          int row = m0 + wr * 64 + mi * 16 + (lane >> 4) * 4 + r;
          float v = acc[mi][ni][r] + b;
          oh[(size_t)row * DI + col] = f2bf(v);
          if (z == 0) rowsq[mi][r] += v * v;
        }
    }
    if (z == 0) {
#pragma unroll
      for (int mi = 0; mi < 4; ++mi)
#pragma unroll
        for (int r = 0; r < 4; ++r) {
          float s = rowsq[mi][r];
          s += __shfl_xor(s, 1); s += __shfl_xor(s, 2);
          s += __shfl_xor(s, 4); s += __shfl_xor(s, 8);
          if ((lane & 15) == 0) {
            int row = m0 + wr * 64 + mi * 16 + (lane >> 4) * 4 + r;
            qnp[(size_t)(blockIdx.x * 2 + wc) * NR + row] = s;
          }
        }
    }
  } else {
    // v: store transposed vt[d][i] bf16, packing 4 consecutive rows per lane
#pragma unroll
    for (int ni = 0; ni < 4; ++ni) {
      int col = n0 + wc * 64 + ni * 16 + (lane & 15);
      float b = bias[col];
#pragma unroll
      for (int mi = 0; mi < 4; ++mi) {
        int rowb = m0 + wr * 64 + mi * 16 + (lane >> 4) * 4;
        ushort4 pk;
        pk.x = f2bf(acc[mi][ni][0] + b);
        pk.y = f2bf(acc[mi][ni][1] + b);
        pk.z = f2bf(acc[mi][ni][2] + b);
        pk.w = f2bf(acc[mi][ni][3] + b);
        *(ushort4*)(vt + (size_t)col * NR + rowb) = pk;
      }
    }
  }
}

// ---------------- K1b: c_i = 5*|q_i| + 10 ----------------
__global__ void k_cvec(const float* __restrict__ qnp, float* __restrict__ cvec) {
  int i = blockIdx.x * 256 + threadIdx.x;  // grid 32 x 256 = 8192
  float s = 0.f;
#pragma unroll
  for (int t = 0; t < 8; ++t) s += qnp[(size_t)t * NR + i];
  cvec[i] = 5.0f * sqrtf(s) + 10.f;
}

// ---------------- K2: P = exp(qhi·khi - c_row), partial row sums ----------
__global__ __launch_bounds__(256, 4) void k_scores(
    const u16* __restrict__ qhi, const u16* __restrict__ khi,
    const float* __restrict__ cvec,
    u16* __restrict__ P, float* __restrict__ psum) {
  __shared__ __align__(16) u16 sA[128 * 64], sB[128 * 64];
  const int m0 = blockIdx.y * 128, n0 = blockIdx.x * 128;
  const int lane = threadIdx.x & 63, wid = threadIdx.x >> 6;
  const int wr = wid >> 1, wc = wid & 1;
  f32x4 acc[4][4] = {};
  const bool isA = wid < 2;
  const u16* gS = isA ? qhi : khi;
  u16* Dst = isA ? sA : sB;
  const int gb = isA ? m0 : n0;
  const int rbase = (wid & 1) * 64;

  for (int kt = 0; kt < 8; ++kt) {
#pragma unroll
    for (int c = 0; c < 8; ++c) {
      int row = rbase + c * 8 + (lane >> 3);
      int srck = kt * 64 + (((lane & 7) ^ (row & 7)) << 3);
      load_lds16(gS + (size_t)(gb + row) * DI + srck,
                 (char*)Dst + (size_t)(rbase + c * 8) * 128);
    }
    __syncthreads();
#pragma unroll
    for (int dt = 0; dt < 2; ++dt) {
      short8 a[4], b[4];
      int kb = dt * 64 + ((lane >> 4) << 4);
#pragma unroll
      for (int t = 0; t < 4; ++t) {
        int ra = wr * 64 + t * 16 + (lane & 15);
        a[t] = *(const short8*)((const char*)sA + ra * 128 + (kb ^ ((ra & 7) << 4)));
        int rb = wc * 64 + t * 16 + (lane & 15);
        b[t] = *(const short8*)((const char*)sB + rb * 128 + (kb ^ ((rb & 7) << 4)));
      }
#pragma unroll
      for (int mi = 0; mi < 4; ++mi)
#pragma unroll
        for (int ni = 0; ni < 4; ++ni)
          acc[mi][ni] = __builtin_amdgcn_mfma_f32_16x16x32_bf16(a[mi], b[ni], acc[mi][ni], 0, 0, 0);
    }
    __syncthreads();
  }

  float cr[4][4];
#pragma unroll
  for (int mi = 0; mi < 4; ++mi)
#pragma unroll
    for (int r = 0; r < 4; ++r)
      cr[mi][r] = cvec[m0 + wr * 64 + mi * 16 + (lane >> 4) * 4 + r];

  float ps[4][4] = {};
#pragma unroll
  for (int ni = 0; ni < 4; ++ni) {
    int col = n0 + wc * 64 + ni * 16 + (lane & 15);
#pragma unroll
    for (int mi = 0; mi < 4; ++mi)
#pragma unroll
      for (int r = 0; r < 4; ++r) {
        int row = m0 + wr * 64 + mi * 16 + (lane >> 4) * 4 + r;
        float a = fminf(acc[mi][ni][r] - cr[mi][r], 60.f);  // overflow guard
        float p = __expf(a);
        P[(size_t)row * NR + col] = f2bf(p);
        ps[mi][r] += p;
      }
  }
#pragma unroll
  for (int mi = 0; mi < 4; ++mi)
#pragma unroll
    for (int r = 0; r < 4; ++r) {
      float s = ps[mi][r];
      s += __shfl_xor(s, 1); s += __shfl_xor(s, 2);
      s += __shfl_xor(s, 4); s += __shfl_xor(s, 8);
      if ((lane & 15) == 0) {
        int row = m0 + wr * 64 + mi * 16 + (lane >> 4) * 4 + r;
        psum[(size_t)(blockIdx.x * 2 + wc) * NR + row] = s;
      }
    }
}

// ---------------- K3: row sums -> 1/sum (guarded) ----------------
__global__ void k_rowsum(const float* __restrict__ psum, float* __restrict__ rinv) {
  int i = blockIdx.x * 256 + threadIdx.x;  // 8192 threads
  float s = 0.f;
  for (int t = 0; t < 128; ++t) s += psum[(size_t)t * NR + i];
  rinv[i] = (s > 0.f) ? 1.f / s : 0.f;
}

// ---------------- K4: O_partial = P @ V (nx=1: full 512-col output) -------
// Grid (1, 64, 4) = 256 blocks, 1024 threads (16 waves, 4x4 wave grid,
// per-wave 32m x 128n, acc[2][8]). P streamed exactly once; vt B-tile is
// identical for all blocks of a z -> L2-resident. LDS 16+64 = 80 KB.
__global__ __launch_bounds__(1024, 4) void k_pv(
    const u16* __restrict__ P, const u16* __restrict__ vt,
    u16* __restrict__ Opart) {
  __shared__ __align__(16) u16 sA[128 * 64], sB[512 * 64];
  const int m0 = blockIdx.y * 128;
  const int z = blockIdx.z;
  const int lane = threadIdx.x & 63;
  const int wid = threadIdx.x >> 6;           // 0..15
  const int wr = wid >> 2, wc = wid & 3;      // 4x4 wave grid

  f32x4 acc[2][8] = {};

  for (int kt = 0; kt < 32; ++kt) {
    int kg = z * 2048 + kt * 64;
    // 80 chunks of 1KB (A: 0..15 = P rows, B: 16..79 = vt rows), 5/wave
#pragma unroll
    for (int c = 0; c < 5; ++c) {
      int cc = wid * 5 + c;                   // 0..79
      bool isA = cc < 16;
      int ch = isA ? cc : cc - 16;            // A 0..15, B 0..63
      int row = ch * 8 + (lane >> 3);         // A 0..127, B 0..511
      int col16 = (lane & 7) ^ (row & 7);
      const u16* src = isA ? P : vt;
      u16* dst = isA ? sA : sB;
      int gb = isA ? (m0 + row) : row;
      load_lds16(src + (size_t)gb * NR + kg + col16 * 8,
                 (char*)dst + ch * 1024);
    }
    __syncthreads();
#pragma unroll
    for (int dt = 0; dt < 2; ++dt) {
      short8 a[2], b[8];
      int kb = dt * 64 + ((lane >> 4) << 4);
#pragma unroll
      for (int t = 0; t < 2; ++t) {
        int ra = wr * 32 + t * 16 + (lane & 15);
        a[t] = *(const short8*)((const char*)sA + ra * 128 + (kb ^ ((ra & 7) << 4)));
      }
#pragma unroll
      for (int t = 0; t < 8; ++t) {
        int rb = wc * 128 + t * 16 + (lane & 15);
        b[t] = *(const short8*)((const char*)sB + rb * 128 + (kb ^ ((rb & 7) << 4)));
      }
#pragma unroll
      for (int mi = 0; mi < 2; ++mi)
#pragma unroll
        for (int ni = 0; ni < 8; ++ni)
          acc[mi][ni] = __builtin_amdgcn_mfma_f32_16x16x32_bf16(a[mi], b[ni], acc[mi][ni], 0, 0, 0);
    }
    __syncthreads();
  }
#pragma unroll
  for (int ni = 0; ni < 8; ++ni) {
    int col = wc * 128 + ni * 16 + (lane & 15);
#pragma unroll
    for (int mi = 0; mi < 2; ++mi)
#pragma unroll
      for (int r = 0; r < 4; ++r) {
        int row = m0 + wr * 32 + mi * 16 + (lane >> 4) * 4 + r;
        Opart[((size_t)z * NR + row) * DI + col] = f2bf(acc[mi][ni][r]);
      }
  }
}

// ---------------- K5: h = x + (sum Op)*rinv; LayerNorm; col partials ------
__global__ __launch_bounds__(256) void k_ln(const u16* __restrict__ Opart,
                                            const float* __restrict__ x,
                                            const float* __restrict__ rinv,
                                            const float* __restrict__ gamma,
                                            const float* __restrict__ beta,
                                            float* __restrict__ part) {
  const int lane = threadIdx.x & 63;
  const int w = threadIdx.x >> 6;
  float4 g0 = *(const float4*)(gamma + lane * 8);
  float4 g1 = *(const float4*)(gamma + lane * 8 + 4);
  float4 b0 = *(const float4*)(beta + lane * 8);
  float4 b1 = *(const float4*)(beta + lane * 8 + 4);
  float ga[8] = {g0.x, g0.y, g0.z, g0.w, g1.x, g1.y, g1.z, g1.w};
  float be[8] = {b0.x, b0.y, b0.z, b0.w, b1.x, b1.y, b1.z, b1.w};
  float colacc[8] = {0, 0, 0, 0, 0, 0, 0, 0};
  const size_t slab = (size_t)NR * DI;
  for (int it = 0; it < 32; ++it) {
    int row = blockIdx.x * 128 + it * 4 + w;
    float rv = rinv[row];
    const u16* ob = Opart + (size_t)row * DI + lane * 8;
    const float* xr = x + (size_t)row * DI + lane * 8;
    short8 s0 = *(const short8*)(ob);
    short8 s1 = *(const short8*)(ob + slab);
    short8 s2 = *(const short8*)(ob + 2 * slab);
    short8 s3 = *(const short8*)(ob + 3 * slab);
    float4 xa = *(const float4*)xr;
    float4 xb = *(const float4*)(xr + 4);
    float xv[8] = {xa.x, xa.y, xa.z, xa.w, xb.x, xb.y, xb.z, xb.w};
    float v[8];
#pragma unroll
    for (int j = 0; j < 8; ++j)
      v[j] = (bf2f((u16)s0[j]) + bf2f((u16)s1[j]) +
              bf2f((u16)s2[j]) + bf2f((u16)s3[j])) * rv + xv[j];
    float s1s = 0.f, s2s = 0.f;
#pragma unroll
    for (int j = 0; j < 8; ++j) { s1s += v[j]; s2s += v[j] * v[j]; }
#pragma unroll
    for (int m = 1; m < 64; m <<= 1) { s1s += __shfl_xor(s1s, m); s2s += __shfl_xor(s2s, m); }
    float mean = s1s * (1.f / DI);
    float var = fmaxf(s2s * (1.f / DI) - mean * mean, 0.f);
    float rstd = rsqrtf(var + 1e-5f);
#pragma unroll
    for (int j = 0; j < 8; ++j) colacc[j] += (v[j] - mean) * rstd * ga[j] + be[j];
  }
  __shared__ float red[4][DI];
#pragma unroll
  for (int j = 0; j < 8; ++j) red[w][lane * 8 + j] = colacc[j];
  __syncthreads();
  for (int d = threadIdx.x; d < DI; d += 256)
    part[(size_t)blockIdx.x * DI + d] = red[0][d] + red[1][d] + red[2][d] + red[3][d];
}

// ---------------- K6: final mean ----------------
__global__ void k_final(const float* __restrict__ part, float* __restrict__ out) {
  int d = threadIdx.x;  // 512 threads
  float s = 0.f;
  for (int t = 0; t < 64; ++t) s += part[(size_t)t * DI + d];
  out[d] = s * (1.f / NR);
}

extern "C" void kernel_launch(void* const* d_in, const int* in_sizes, int n_in,
                              void* d_out, int out_size, void* d_ws, size_t ws_size,
                              hipStream_t stream) {
  (void)in_sizes; (void)n_in; (void)out_size; (void)ws_size;
  const float* x = (const float*)d_in[0];
  const float* wq = (const float*)d_in[1];
  const float* bq = (const float*)d_in[2];
  const float* wk = (const float*)d_in[3];
  const float* bk = (const float*)d_in[4];
  const float* wv = (const float*)d_in[5];
  const float* bv = (const float*)d_in[6];
  const float* gamma = (const float*)d_in[7];
  const float* beta = (const float*)d_in[8];
  float* out = (float*)d_out;

  char* cur = (char*)d_ws;
  auto alloc = [&](size_t bytes) -> char* {
    char* p = cur;
    cur += (bytes + 255) & ~(size_t)255;
    return p;
  };
  u16* xhi = (u16*)alloc((size_t)NR * DI * 2);
  u16* whi = (u16*)alloc((size_t)3 * DI * DI * 2);
  u16* qhi = (u16*)alloc((size_t)NR * DI * 2);
  u16* khi = (u16*)alloc((size_t)NR * DI * 2);
  u16* vt = (u16*)alloc((size_t)DI * NR * 2);
  float* qnp = (float*)alloc((size_t)8 * NR * 4);
  float* cvec = (float*)alloc((size_t)NR * 4);
  float* psum = (float*)alloc((size_t)128 * NR * 4);
  float* rinv = (float*)alloc((size_t)NR * 4);
  u16* P = (u16*)alloc((size_t)NR * NR * 2);
  u16* Opart = (u16*)alloc((size_t)4 * NR * DI * 2);
  float* part = (float*)alloc((size_t)64 * DI * 4);

  k_prep<<<1024, 256, 0, stream>>>(x, wq, wk, wv, xhi, whi);
  k_qkv<<<dim3(4, 64, 3), 256, 0, stream>>>(xhi, whi, bq, bk, bv,
                                            qhi, khi, vt, qnp);
  k_cvec<<<32, 256, 0, stream>>>(qnp, cvec);
  k_scores<<<dim3(64, 64), 256, 0, stream>>>(qhi, khi, cvec, P, psum);
  k_rowsum<<<32, 256, 0, stream>>>(psum, rinv);
  k_pv<<<dim3(1, 64, 4), 1024, 0, stream>>>(P, vt, Opart);
  k_ln<<<64, 256, 0, stream>>>(Opart, x, rinv, gamma, beta, part);
  k_final<<<1, 512, 0, stream>>>(part, out);
}